// Round 1
// baseline (63.769 us; speedup 1.0000x reference)
//
#include <hip/hip_runtime.h>

#define BB 32
#define CC 3
#define HH 512
#define WW 512

__global__ __launch_bounds__(256) void warp_kernel(const float* __restrict__ img,
                                                   const float* __restrict__ Htf,
                                                   float* __restrict__ out) {
    const int HW = HH * WW;
    int i = blockIdx.x * 256 + threadIdx.x;   // pixel id over B*H*W
    int b = i >> 18;                          // / (512*512)
    int pix = i & (HW - 1);
    int h = pix >> 9;
    int w = pix & (WW - 1);

    // b is uniform across the block -> these become scalar loads
    const float* Hp = Htf + b * 9;
    float h00 = Hp[0], h01 = Hp[1], h02 = Hp[2];
    float h10 = Hp[3], h11 = Hp[4], h12 = Hp[5];
    float h20 = Hp[6], h21 = Hp[7], h22 = Hp[8];

    float gx = -1.0f + 2.0f * (float)w / (float)(WW - 1);
    float gy = -1.0f + 2.0f * (float)h / (float)(HH - 1);

    float X = h00 * gx + h01 * gy + h02;
    float Y = h10 * gx + h11 * gy + h12;
    float T = h20 * gx + h21 * gy + h22;
    float rT = 1.0f / T;
    float x = X * rT;
    float y = Y * rT;

    float px = (x + 1.0f) * (WW * 0.5f);
    float py = (y + 1.0f) * (HH * 0.5f);

    float fx = floorf(px), fy = floorf(py);
    float x0 = fminf(fmaxf(fx,        0.0f), (float)(WW - 1));
    float x1 = fminf(fmaxf(fx + 1.0f, 0.0f), (float)(WW - 1));
    float y0 = fminf(fmaxf(fy,        0.0f), (float)(HH - 1));
    float y1 = fminf(fmaxf(fy + 1.0f, 0.0f), (float)(HH - 1));

    // weights from CLIPPED corners, matching the reference exactly
    float wa = (x1 - px) * (y1 - py);
    float wb = (x1 - px) * (py - y0);
    float wc = (px - x0) * (y1 - py);
    float wd = (px - x0) * (py - y0);

    int ix0 = (int)x0, ix1 = (int)x1, iy0 = (int)y0, iy1 = (int)y1;

    int oa = iy0 * WW + ix0;
    int ob = iy1 * WW + ix0;
    int oc = iy0 * WW + ix1;
    int od = iy1 * WW + ix1;

    const float* ib   = img + (size_t)b * (CC * HW);
    float*       outb = out + (size_t)b * (CC * HW);

#pragma unroll
    for (int c = 0; c < CC; ++c) {
        const float* p = ib + c * HW;
        float v = wa * p[oa] + wb * p[ob] + wc * p[oc] + wd * p[od];
        outb[c * HW + pix] = v;
    }
}

extern "C" void kernel_launch(void* const* d_in, const int* in_sizes, int n_in,
                              void* d_out, int out_size, void* d_ws, size_t ws_size,
                              hipStream_t stream) {
    const float* img = (const float*)d_in[0];
    const float* Htf = (const float*)d_in[1];
    float* out = (float*)d_out;

    int total_pixels = BB * HH * WW;          // 8,388,608
    int blocks = total_pixels / 256;          // 32,768
    warp_kernel<<<blocks, 256, 0, stream>>>(img, Htf, out);
}